// Round 1
// baseline (2656.435 us; speedup 1.0000x reference)
//
#include <hip/hip_runtime.h>
#include <cstdint>
#include <cstddef>

#define DIM 128

// ---------------- degree ----------------
__global__ __launch_bounds__(256) void deg_kernel(const int* __restrict__ row,
                                                  float* __restrict__ deg, int E) {
    int e = blockIdx.x * 256 + threadIdx.x;
    if (e < E) atomicAdd(&deg[row[e]], 1.0f);
}

__global__ __launch_bounds__(256) void dinv_kernel(float* __restrict__ d, int n) {
    int i = blockIdx.x * 256 + threadIdx.x;
    if (i < n) {
        float v = fmaxf(d[i], 1.0f);
        d[i] = 1.0f / sqrtf(v);
    }
}

// ---------------- transform: h1 = hin @ Wt^T + bt ; a = tanh(h1.Wg + bg)*dinv ----
// One thread per node. Wt/bt/Wg indices are wave-uniform -> scalar loads (SMEM
// pipe) overlap with VALU FMAs. h row reloaded per j-segment (L1-cached).
__global__ __launch_bounds__(64) void transform_kernel(
    const float* __restrict__ hin, const float* __restrict__ Wt,
    const float* __restrict__ bt, const float* __restrict__ Wg,
    const float* __restrict__ bg, const float* __restrict__ dinv,
    float* __restrict__ h1, float* __restrict__ acc, float* __restrict__ aout,
    int n)
{
    int i = blockIdx.x * 64 + threadIdx.x;
    if (i >= n) return;
    const float4* hrow = (const float4*)(hin + (size_t)i * DIM);
    float p = 0.0f;
    for (int js = 0; js < 4; ++js) {
        float accv[32];
#pragma unroll
        for (int jj = 0; jj < 32; ++jj) accv[jj] = bt[js * 32 + jj];
        for (int ks = 0; ks < 4; ++ks) {
            float4 h4[8];
#pragma unroll
            for (int q = 0; q < 8; ++q) h4[q] = hrow[ks * 8 + q];
#pragma unroll
            for (int jj = 0; jj < 32; ++jj) {
                const float4* w4p = (const float4*)(Wt + (size_t)(js * 32 + jj) * DIM + ks * 32);
                float s = 0.0f;
#pragma unroll
                for (int q = 0; q < 8; ++q) {
                    float4 w = w4p[q];
                    s += h4[q].x * w.x;
                    s += h4[q].y * w.y;
                    s += h4[q].z * w.z;
                    s += h4[q].w * w.w;
                }
                accv[jj] += s;
            }
        }
#pragma unroll
        for (int jj = 0; jj < 32; ++jj) p += accv[jj] * Wg[js * 32 + jj];
        float4* h1p = (float4*)(h1 + (size_t)i * DIM + js * 32);
        float4* acp = (float4*)(acc + (size_t)i * DIM + js * 32);
#pragma unroll
        for (int q = 0; q < 8; ++q) {
            float4 v = make_float4(accv[q * 4 + 0], accv[q * 4 + 1],
                                   accv[q * 4 + 2], accv[q * 4 + 3]);
            h1p[q] = v;
            acp[q] = v;  // residual init: acc starts at h1
        }
    }
    aout[i] = tanhf(p + bg[0]) * dinv[i];
}

// ---------------- per-edge scalar norm ----------------
__global__ __launch_bounds__(256) void edge_norm_kernel(
    const int* __restrict__ row, const int* __restrict__ col,
    const float* __restrict__ a, const float* __restrict__ dinv,
    float* __restrict__ norm, int E)
{
    int e = blockIdx.x * 256 + threadIdx.x;
    if (e < E) norm[e] = a[row[e]] * dinv[col[e]];
}

// ---------------- message scatter: acc[col] += norm * h1[row] ----------------
// 32 threads (float4 each) per edge; gather coalesced 512B, scatter via fp32
// hardware atomics.
__global__ __launch_bounds__(256) void edge_msg_kernel(
    const int* __restrict__ row, const int* __restrict__ col,
    const float* __restrict__ norm, const float* __restrict__ h1,
    float* __restrict__ acc, int E)
{
    int idx = blockIdx.x * 256 + threadIdx.x;
    int e = idx >> 5;
    int q = idx & 31;
    if (e >= E) return;
    float nv = norm[e];
    int r = row[e];
    int c = col[e];
    float4 v = ((const float4*)(h1 + (size_t)r * DIM))[q];
    float* dst = acc + (size_t)c * DIM + q * 4;
#if defined(__HIP_DEVICE_COMPILE__)
    unsafeAtomicAdd(dst + 0, nv * v.x);
    unsafeAtomicAdd(dst + 1, nv * v.y);
    unsafeAtomicAdd(dst + 2, nv * v.z);
    unsafeAtomicAdd(dst + 3, nv * v.w);
#else
    atomicAdd(dst + 0, nv * v.x);
    atomicAdd(dst + 1, nv * v.y);
    atomicAdd(dst + 2, nv * v.z);
    atomicAdd(dst + 3, nv * v.w);
#endif
}

// ---------------- relu ----------------
__global__ __launch_bounds__(256) void relu_kernel(const float* __restrict__ in,
                                                   float* __restrict__ out, int n4) {
    int i = blockIdx.x * 256 + threadIdx.x;
    if (i < n4) {
        float4 v = ((const float4*)in)[i];
        v.x = fmaxf(v.x, 0.0f);
        v.y = fmaxf(v.y, 0.0f);
        v.z = fmaxf(v.z, 0.0f);
        v.w = fmaxf(v.w, 0.0f);
        ((float4*)out)[i] = v;
    }
}

extern "C" void kernel_launch(void* const* d_in, const int* in_sizes, int n_in,
                              void* d_out, int out_size, void* d_ws, size_t ws_size,
                              hipStream_t stream) {
    const float* x    = (const float*)d_in[0];
    const int*   edge = (const int*)d_in[1];
    const float* Wt   = (const float*)d_in[2];
    const float* bt   = (const float*)d_in[3];
    const float* Wg   = (const float*)d_in[4];
    const float* bg   = (const float*)d_in[5];
    float* out = (float*)d_out;

    const int n = in_sizes[0] / DIM;      // 50000
    const int E = in_sizes[1] / 2;        // 600000
    const int* row = edge;
    const int* col = edge + E;

    // workspace layout (floats)
    float* ws    = (float*)d_ws;
    float* dinv  = ws;                    // n (also used as deg accumulator)
    float* a     = ws + 50048;            // n
    float* norm  = ws + 100096;           // E
    float* h1    = ws + 700160;           // n*DIM
    float* hbuf  = ws + 7100160;          // n*DIM

    const int n4 = n * DIM / 4;

    // degree -> dinv (edge-structure only; shared by both layers)
    hipMemsetAsync(dinv, 0, (size_t)n * sizeof(float), stream);
    deg_kernel<<<(E + 255) / 256, 256, 0, stream>>>(row, dinv, E);
    dinv_kernel<<<(n + 255) / 256, 256, 0, stream>>>(dinv, n);

    for (int l = 0; l < 2; ++l) {
        const float* hin = (l == 0) ? x : hbuf;
        const float* Wtl = Wt + (size_t)l * DIM * DIM;
        const float* btl = bt + (size_t)l * DIM;
        const float* Wgl = Wg + (size_t)l * DIM;
        const float* bgl = bg + l;

        transform_kernel<<<(n + 63) / 64, 64, 0, stream>>>(
            hin, Wtl, btl, Wgl, bgl, dinv, h1, out, a, n);
        edge_norm_kernel<<<(E + 255) / 256, 256, 0, stream>>>(row, col, a, dinv, norm, E);
        edge_msg_kernel<<<(E * 32 + 255) / 256, 256, 0, stream>>>(row, col, norm, h1, out, E);
        if (l == 0) {
            relu_kernel<<<(n4 + 255) / 256, 256, 0, stream>>>(out, hbuf, n4);
        } else {
            relu_kernel<<<(n4 + 255) / 256, 256, 0, stream>>>(out, out, n4);
        }
    }
}

// Round 2
// 758.200 us; speedup vs baseline: 3.5036x; 3.5036x over previous
//
#include <hip/hip_runtime.h>
#include <cstdint>
#include <cstddef>

#define DIM 128

// ---------------- histogram: in-degree (by col) and out-degree (by row) -----
__global__ __launch_bounds__(256) void hist_kernel(const int* __restrict__ row,
                                                   const int* __restrict__ col,
                                                   int* __restrict__ degi,
                                                   int* __restrict__ cnt, int E) {
    int e = blockIdx.x * 256 + threadIdx.x;
    if (e < E) {
        atomicAdd(&degi[row[e]], 1);
        atomicAdd(&cnt[col[e]], 1);
    }
}

// ---------------- 3-phase exclusive scan of cnt -> off ----------------------
__global__ __launch_bounds__(256) void scan1_kernel(const int* __restrict__ cnt,
                                                    int* __restrict__ bsum, int n) {
    __shared__ int buf[256];
    int i = blockIdx.x * 256 + threadIdx.x;
    buf[threadIdx.x] = (i < n) ? cnt[i] : 0;
    __syncthreads();
    for (int s = 128; s > 0; s >>= 1) {
        if (threadIdx.x < s) buf[threadIdx.x] += buf[threadIdx.x + s];
        __syncthreads();
    }
    if (threadIdx.x == 0) bsum[blockIdx.x] = buf[0];
}

__global__ __launch_bounds__(256) void scan2_kernel(int* __restrict__ bsum, int nb) {
    __shared__ int buf[256];
    int tid = threadIdx.x;
    int v = (tid < nb) ? bsum[tid] : 0;
    buf[tid] = v;
    __syncthreads();
    for (int s = 1; s < 256; s <<= 1) {
        int add = (tid >= s) ? buf[tid - s] : 0;
        __syncthreads();
        buf[tid] += add;
        __syncthreads();
    }
    if (tid < nb) bsum[tid] = buf[tid] - v;  // exclusive block offsets
}

// writes off[] (exclusive) and re-initializes cnt[] as the scatter cursor
__global__ __launch_bounds__(256) void scan3_kernel(int* __restrict__ cnt,
                                                    const int* __restrict__ bsum,
                                                    int* __restrict__ off, int n) {
    __shared__ int buf[256];
    int tid = threadIdx.x;
    int i = blockIdx.x * 256 + tid;
    int v = (i < n) ? cnt[i] : 0;
    buf[tid] = v;
    __syncthreads();
    for (int s = 1; s < 256; s <<= 1) {
        int add = (tid >= s) ? buf[tid - s] : 0;
        __syncthreads();
        buf[tid] += add;
        __syncthreads();
    }
    int excl = bsum[blockIdx.x] + buf[tid] - v;
    if (i < n) { off[i] = excl; cnt[i] = excl; }
    if (i == n - 1) off[n] = excl + v;
}

__global__ __launch_bounds__(256) void dinv_kernel(const int* __restrict__ degi,
                                                   float* __restrict__ dinv, int n) {
    int i = blockIdx.x * 256 + threadIdx.x;
    if (i < n) dinv[i] = rsqrtf(fmaxf((float)degi[i], 1.0f));
}

__global__ __launch_bounds__(256) void scatter_kernel(const int* __restrict__ row,
                                                      const int* __restrict__ col,
                                                      int* __restrict__ cursor,
                                                      int* __restrict__ csr_row, int E) {
    int e = blockIdx.x * 256 + threadIdx.x;
    if (e < E) {
        int slot = atomicAdd(&cursor[col[e]], 1);
        csr_row[slot] = row[e];
    }
}

// ---------------- transform: h1 = hin @ Wt^T + bt ; a = tanh(h1.Wg + bg)*dinv
__global__ __launch_bounds__(64) void transform_kernel(
    const float* __restrict__ hin, const float* __restrict__ Wt,
    const float* __restrict__ bt, const float* __restrict__ Wg,
    const float* __restrict__ bg, const float* __restrict__ dinv,
    float* __restrict__ h1, float* __restrict__ aout, int n)
{
    int i = blockIdx.x * 64 + threadIdx.x;
    if (i >= n) return;
    const float4* hrow = (const float4*)(hin + (size_t)i * DIM);
    float p = 0.0f;
    for (int js = 0; js < 4; ++js) {
        float accv[32];
#pragma unroll
        for (int jj = 0; jj < 32; ++jj) accv[jj] = bt[js * 32 + jj];
        for (int ks = 0; ks < 4; ++ks) {
            float4 h4[8];
#pragma unroll
            for (int q = 0; q < 8; ++q) h4[q] = hrow[ks * 8 + q];
#pragma unroll
            for (int jj = 0; jj < 32; ++jj) {
                const float4* w4p = (const float4*)(Wt + (size_t)(js * 32 + jj) * DIM + ks * 32);
                float s = 0.0f;
#pragma unroll
                for (int q = 0; q < 8; ++q) {
                    float4 w = w4p[q];
                    s += h4[q].x * w.x;
                    s += h4[q].y * w.y;
                    s += h4[q].z * w.z;
                    s += h4[q].w * w.w;
                }
                accv[jj] += s;
            }
        }
#pragma unroll
        for (int jj = 0; jj < 32; ++jj) p += accv[jj] * Wg[js * 32 + jj];
        float4* h1p = (float4*)(h1 + (size_t)i * DIM + js * 32);
#pragma unroll
        for (int q = 0; q < 8; ++q) {
            h1p[q] = make_float4(accv[q * 4 + 0], accv[q * 4 + 1],
                                 accv[q * 4 + 2], accv[q * 4 + 3]);
        }
    }
    aout[i] = tanhf(p + bg[0]) * dinv[i];
}

// ---------------- aggregation: out[c] = relu(dinv[c]*sum(a[r]*h1[r]) + h1[c])
// one wave per node; lane owns a float2 slice (64*2 = 128)
__global__ __launch_bounds__(256) void agg_kernel(
    const int* __restrict__ off, const int* __restrict__ csr_row,
    const float* __restrict__ a, const float* __restrict__ dinv,
    const float* __restrict__ h1, float* __restrict__ out, int n)
{
    int node = blockIdx.x * 4 + (threadIdx.x >> 6);
    if (node >= n) return;
    int lane = threadIdx.x & 63;
    int beg = off[node], end = off[node + 1];
    const float2* h2 = (const float2*)h1;
    float2 acc0 = make_float2(0.0f, 0.0f);
    float2 acc1 = make_float2(0.0f, 0.0f);
    int s = beg;
    for (; s + 2 <= end; s += 2) {
        int r0 = csr_row[s];
        int r1 = csr_row[s + 1];
        float a0 = a[r0];
        float a1 = a[r1];
        float2 v0 = h2[(size_t)r0 * 64 + lane];
        float2 v1 = h2[(size_t)r1 * 64 + lane];
        acc0.x += a0 * v0.x; acc0.y += a0 * v0.y;
        acc1.x += a1 * v1.x; acc1.y += a1 * v1.y;
    }
    if (s < end) {
        int r0 = csr_row[s];
        float a0 = a[r0];
        float2 v0 = h2[(size_t)r0 * 64 + lane];
        acc0.x += a0 * v0.x; acc0.y += a0 * v0.y;
    }
    float dv = dinv[node];
    float2 hv = h2[(size_t)node * 64 + lane];
    float2 o;
    o.x = fmaxf(dv * (acc0.x + acc1.x) + hv.x, 0.0f);
    o.y = fmaxf(dv * (acc0.y + acc1.y) + hv.y, 0.0f);
    ((float2*)out)[(size_t)node * 64 + lane] = o;
}

extern "C" void kernel_launch(void* const* d_in, const int* in_sizes, int n_in,
                              void* d_out, int out_size, void* d_ws, size_t ws_size,
                              hipStream_t stream) {
    const float* x    = (const float*)d_in[0];
    const int*   edge = (const int*)d_in[1];
    const float* Wt   = (const float*)d_in[2];
    const float* bt   = (const float*)d_in[3];
    const float* Wg   = (const float*)d_in[4];
    const float* bg   = (const float*)d_in[5];
    float* out = (float*)d_out;

    const int n = in_sizes[0] / DIM;      // 50000
    const int E = in_sizes[1] / 2;        // 600000
    const int* row = edge;
    const int* col = edge + E;

    // workspace layout (float units)
    float* ws   = (float*)d_ws;
    float* h1   = ws;                        // n*DIM = 6,400,000
    float* dinv = ws + 6400000;              // n (pad 50048)
    float* a    = ws + 6450048;              // n
    int*   cnt  = (int*)(ws + 6500096);      // n (also scatter cursor)
    int*   off  = (int*)(ws + 6550144);      // n+1 (pad 50304)
    int*   bsum = (int*)(ws + 6600448);      // 256
    int*   degi = (int*)(ws + 6600704);      // n
    int*   csr  = (int*)(ws + 6650752);      // E

    const int nb = (n + 255) / 256;

    // ---- edge-structure preprocessing (shared by both layers) ----
    hipMemsetAsync(degi, 0, (size_t)n * sizeof(int), stream);
    hipMemsetAsync(cnt, 0, (size_t)n * sizeof(int), stream);
    hist_kernel<<<(E + 255) / 256, 256, 0, stream>>>(row, col, degi, cnt, E);
    scan1_kernel<<<nb, 256, 0, stream>>>(cnt, bsum, n);
    scan2_kernel<<<1, 256, 0, stream>>>(bsum, nb);
    scan3_kernel<<<nb, 256, 0, stream>>>(cnt, bsum, off, n);
    dinv_kernel<<<nb, 256, 0, stream>>>(degi, dinv, n);
    scatter_kernel<<<(E + 255) / 256, 256, 0, stream>>>(row, col, cnt, csr, E);

    // ---- two FA layers ----
    for (int l = 0; l < 2; ++l) {
        const float* hin = (l == 0) ? x : out;
        const float* Wtl = Wt + (size_t)l * DIM * DIM;
        const float* btl = bt + (size_t)l * DIM;
        const float* Wgl = Wg + (size_t)l * DIM;
        const float* bgl = bg + l;

        transform_kernel<<<(n + 63) / 64, 64, 0, stream>>>(
            hin, Wtl, btl, Wgl, bgl, dinv, h1, a, n);
        agg_kernel<<<(n + 3) / 4, 256, 0, stream>>>(off, csr, a, dinv, h1, out, n);
    }
}

// Round 3
// 299.359 us; speedup vs baseline: 8.8738x; 2.5327x over previous
//
#include <hip/hip_runtime.h>
#include <cstdint>
#include <cstddef>

#define DIM 128
#define BM 128

// ---------------- histogram: out-degree (by row) and in-count (by col) -----
__global__ __launch_bounds__(256) void hist_kernel(const int* __restrict__ row,
                                                   const int* __restrict__ col,
                                                   int* __restrict__ degi,
                                                   int* __restrict__ cnt, int E) {
    int e = blockIdx.x * 256 + threadIdx.x;
    if (e < E) {
        atomicAdd(&degi[row[e]], 1);
        atomicAdd(&cnt[col[e]], 1);
    }
}

// ---------------- 3-phase exclusive scan of cnt -> off ----------------------
__global__ __launch_bounds__(256) void scan1_kernel(const int* __restrict__ cnt,
                                                    int* __restrict__ bsum, int n) {
    __shared__ int buf[256];
    int i = blockIdx.x * 256 + threadIdx.x;
    buf[threadIdx.x] = (i < n) ? cnt[i] : 0;
    __syncthreads();
    for (int s = 128; s > 0; s >>= 1) {
        if (threadIdx.x < s) buf[threadIdx.x] += buf[threadIdx.x + s];
        __syncthreads();
    }
    if (threadIdx.x == 0) bsum[blockIdx.x] = buf[0];
}

__global__ __launch_bounds__(256) void scan2_kernel(int* __restrict__ bsum, int nb) {
    __shared__ int buf[256];
    int tid = threadIdx.x;
    int v = (tid < nb) ? bsum[tid] : 0;
    buf[tid] = v;
    __syncthreads();
    for (int s = 1; s < 256; s <<= 1) {
        int add = (tid >= s) ? buf[tid - s] : 0;
        __syncthreads();
        buf[tid] += add;
        __syncthreads();
    }
    if (tid < nb) bsum[tid] = buf[tid] - v;  // exclusive block offsets
}

__global__ __launch_bounds__(256) void scan3_kernel(int* __restrict__ cnt,
                                                    const int* __restrict__ bsum,
                                                    int* __restrict__ off, int n) {
    __shared__ int buf[256];
    int tid = threadIdx.x;
    int i = blockIdx.x * 256 + tid;
    int v = (i < n) ? cnt[i] : 0;
    buf[tid] = v;
    __syncthreads();
    for (int s = 1; s < 256; s <<= 1) {
        int add = (tid >= s) ? buf[tid - s] : 0;
        __syncthreads();
        buf[tid] += add;
        __syncthreads();
    }
    int excl = bsum[blockIdx.x] + buf[tid] - v;
    if (i < n) { off[i] = excl; cnt[i] = excl; }
    if (i == n - 1) off[n] = excl + v;
}

__global__ __launch_bounds__(256) void dinv_kernel(const int* __restrict__ degi,
                                                   float* __restrict__ dinv, int n) {
    int i = blockIdx.x * 256 + threadIdx.x;
    if (i < n) dinv[i] = rsqrtf(fmaxf((float)degi[i], 1.0f));
}

__global__ __launch_bounds__(256) void scatter_kernel(const int* __restrict__ row,
                                                      const int* __restrict__ col,
                                                      int* __restrict__ cursor,
                                                      int* __restrict__ csr_row, int E) {
    int e = blockIdx.x * 256 + threadIdx.x;
    if (e < E) {
        int slot = atomicAdd(&cursor[col[e]], 1);
        csr_row[slot] = row[e];
    }
}

// ---------------- transform: tiled fp32 GEMM in LDS ------------------------
// h1 = hin @ Wt^T + bt ; a = tanh(h1 . Wg + bg) * dinv
// 256 threads, 128-node x 128-col tile, MR=8 x NR=8 register tile.
// XOR swizzle (k4 ^ ((r>>3)^r)&7) kills bank conflicts for both read patterns.
__global__ __launch_bounds__(256) void transform_kernel(
    const float* __restrict__ hin, const float* __restrict__ Wt,
    const float* __restrict__ bt, const float* __restrict__ Wg,
    const float* __restrict__ bg, const float* __restrict__ dinv,
    float* __restrict__ h1, float* __restrict__ aout, int n)
{
    __shared__ float h_s[BM * DIM];     // 64 KB
    __shared__ float w_s[DIM * DIM];    // 64 KB
    __shared__ float p_s[BM * 16];      // 8 KB gate partials

    const int tid = threadIdx.x;
    const int node0 = blockIdx.x * BM;
    const int tn = tid & 15;    // column group (8 cols: tn + 16j)
    const int tm = tid >> 4;    // row group (8 rows: tm*8 + i)

    // ---- stage H tile and W into LDS (swizzled) ----
#pragma unroll
    for (int it = 0; it < 16; ++it) {
        int g = tid + it * 256;          // 4096 float4 slots
        int r = g >> 5;                  // 0..127
        int kk = g & 31;                 // float4 index within row
        int sw = ((r >> 3) ^ r) & 7;
        int src_r = node0 + r;
        if (src_r >= n) src_r = n - 1;   // clamp; outputs guarded later
        float4 hv = *(const float4*)(hin + (size_t)src_r * DIM + kk * 4);
        *(float4*)(h_s + r * DIM + (kk ^ sw) * 4) = hv;
        float4 wv = *(const float4*)(Wt + (size_t)r * DIM + kk * 4);
        *(float4*)(w_s + r * DIM + (kk ^ sw) * 4) = wv;
    }
    __syncthreads();

    // ---- register-tiled GEMM ----
    float acc[8][8];
#pragma unroll
    for (int i = 0; i < 8; ++i)
#pragma unroll
        for (int j = 0; j < 8; ++j) acc[i][j] = 0.0f;

    int swh[8], sww[8];
#pragma unroll
    for (int i = 0; i < 8; ++i) { int m = tm * 8 + i; swh[i] = ((m >> 3) ^ m) & 7; }
#pragma unroll
    for (int j = 0; j < 8; ++j) { int nn = tn + 16 * j; sww[j] = ((nn >> 3) ^ nn) & 7; }

    for (int k4 = 0; k4 < 32; ++k4) {
        float4 hv[8], wv[8];
#pragma unroll
        for (int i = 0; i < 8; ++i)
            hv[i] = *(const float4*)(h_s + (tm * 8 + i) * DIM + (k4 ^ swh[i]) * 4);
#pragma unroll
        for (int j = 0; j < 8; ++j)
            wv[j] = *(const float4*)(w_s + (tn + 16 * j) * DIM + (k4 ^ sww[j]) * 4);
#pragma unroll
        for (int i = 0; i < 8; ++i)
#pragma unroll
            for (int j = 0; j < 8; ++j) {
                acc[i][j] = fmaf(hv[i].x, wv[j].x, acc[i][j]);
                acc[i][j] = fmaf(hv[i].y, wv[j].y, acc[i][j]);
                acc[i][j] = fmaf(hv[i].z, wv[j].z, acc[i][j]);
                acc[i][j] = fmaf(hv[i].w, wv[j].w, acc[i][j]);
            }
    }
    __syncthreads();  // before reusing h_s as output staging

    // ---- epilogue: bias, gate partials, swizzled store into h_s ----
    float btr[8], wgr[8];
#pragma unroll
    for (int j = 0; j < 8; ++j) {
        btr[j] = bt[tn + 16 * j];
        wgr[j] = Wg[tn + 16 * j];
    }
#pragma unroll
    for (int i = 0; i < 8; ++i) {
        int m = tm * 8 + i;
        int sw = swh[i];
        float p = 0.0f;
#pragma unroll
        for (int j = 0; j < 8; ++j) {
            float v = acc[i][j] + btr[j];
            p = fmaf(v, wgr[j], p);
            int nn = tn + 16 * j;
            h_s[m * DIM + ((nn >> 2) ^ sw) * 4 + (nn & 3)] = v;
        }
        p_s[m * 16 + tn] = p;
    }
    __syncthreads();

    // ---- coalesced copy-out (unswizzle) ----
#pragma unroll
    for (int it = 0; it < 16; ++it) {
        int g = tid + it * 256;
        int r = g >> 5;
        int kk = g & 31;
        int sw = ((r >> 3) ^ r) & 7;
        float4 v = *(const float4*)(h_s + r * DIM + (kk ^ sw) * 4);
        int dst_r = node0 + r;
        if (dst_r < n) *(float4*)(h1 + (size_t)dst_r * DIM + kk * 4) = v;
    }

    // ---- finalize gate: a = tanh(p + bg) * dinv ----
    if (tid < BM) {
        int node = node0 + tid;
        if (node < n) {
            float s = 0.0f;
#pragma unroll
            for (int t = 0; t < 16; ++t) s += p_s[tid * 16 + t];
            aout[node] = tanhf(s + bg[0]) * dinv[node];
        }
    }
}

// ---------------- aggregation: out[c] = relu(dinv[c]*sum(a[r]*h1[r]) + h1[c])
__global__ __launch_bounds__(256) void agg_kernel(
    const int* __restrict__ off, const int* __restrict__ csr_row,
    const float* __restrict__ a, const float* __restrict__ dinv,
    const float* __restrict__ h1, float* __restrict__ out, int n)
{
    int node = blockIdx.x * 4 + (threadIdx.x >> 6);
    if (node >= n) return;
    int lane = threadIdx.x & 63;
    int beg = off[node], end = off[node + 1];
    const float2* h2 = (const float2*)h1;
    float2 acc0 = make_float2(0.0f, 0.0f);
    float2 acc1 = make_float2(0.0f, 0.0f);
    int s = beg;
    for (; s + 2 <= end; s += 2) {
        int r0 = csr_row[s];
        int r1 = csr_row[s + 1];
        float a0 = a[r0];
        float a1 = a[r1];
        float2 v0 = h2[(size_t)r0 * 64 + lane];
        float2 v1 = h2[(size_t)r1 * 64 + lane];
        acc0.x += a0 * v0.x; acc0.y += a0 * v0.y;
        acc1.x += a1 * v1.x; acc1.y += a1 * v1.y;
    }
    if (s < end) {
        int r0 = csr_row[s];
        float a0 = a[r0];
        float2 v0 = h2[(size_t)r0 * 64 + lane];
        acc0.x += a0 * v0.x; acc0.y += a0 * v0.y;
    }
    float dv = dinv[node];
    float2 hv = h2[(size_t)node * 64 + lane];
    float2 o;
    o.x = fmaxf(dv * (acc0.x + acc1.x) + hv.x, 0.0f);
    o.y = fmaxf(dv * (acc0.y + acc1.y) + hv.y, 0.0f);
    ((float2*)out)[(size_t)node * 64 + lane] = o;
}

extern "C" void kernel_launch(void* const* d_in, const int* in_sizes, int n_in,
                              void* d_out, int out_size, void* d_ws, size_t ws_size,
                              hipStream_t stream) {
    const float* x    = (const float*)d_in[0];
    const int*   edge = (const int*)d_in[1];
    const float* Wt   = (const float*)d_in[2];
    const float* bt   = (const float*)d_in[3];
    const float* Wg   = (const float*)d_in[4];
    const float* bg   = (const float*)d_in[5];
    float* out = (float*)d_out;

    const int n = in_sizes[0] / DIM;      // 50000
    const int E = in_sizes[1] / 2;        // 600000
    const int* row = edge;
    const int* col = edge + E;

    // workspace layout (float units)
    float* ws   = (float*)d_ws;
    float* h1   = ws;                        // n*DIM = 6,400,000
    float* dinv = ws + 6400000;              // n (pad 50048)
    float* a    = ws + 6450048;              // n
    int*   cnt  = (int*)(ws + 6500096);      // n (also scatter cursor)
    int*   off  = (int*)(ws + 6550144);      // n+1 (pad 50304)
    int*   bsum = (int*)(ws + 6600448);      // 256
    int*   degi = (int*)(ws + 6600704);      // n
    int*   csr  = (int*)(ws + 6650752);      // E

    const int nb = (n + 255) / 256;

    // ---- edge-structure preprocessing (shared by both layers) ----
    hipMemsetAsync(degi, 0, (size_t)n * sizeof(int), stream);
    hipMemsetAsync(cnt, 0, (size_t)n * sizeof(int), stream);
    hist_kernel<<<(E + 255) / 256, 256, 0, stream>>>(row, col, degi, cnt, E);
    scan1_kernel<<<nb, 256, 0, stream>>>(cnt, bsum, n);
    scan2_kernel<<<1, 256, 0, stream>>>(bsum, nb);
    scan3_kernel<<<nb, 256, 0, stream>>>(cnt, bsum, off, n);
    dinv_kernel<<<nb, 256, 0, stream>>>(degi, dinv, n);
    scatter_kernel<<<(E + 255) / 256, 256, 0, stream>>>(row, col, cnt, csr, E);

    // ---- two FA layers ----
    const int gt = (n + BM - 1) / BM;
    for (int l = 0; l < 2; ++l) {
        const float* hin = (l == 0) ? x : out;
        const float* Wtl = Wt + (size_t)l * DIM * DIM;
        const float* btl = bt + (size_t)l * DIM;
        const float* Wgl = Wg + (size_t)l * DIM;
        const float* bgl = bg + l;

        transform_kernel<<<gt, 256, 0, stream>>>(
            hin, Wtl, btl, Wgl, bgl, dinv, h1, a, n);
        agg_kernel<<<(n + 3) / 4, 256, 0, stream>>>(off, csr, a, dinv, h1, out, n);
    }
}

// Round 4
// 194.474 us; speedup vs baseline: 13.6596x; 1.5393x over previous
//
#include <hip/hip_runtime.h>
#include <cstdint>
#include <cstddef>

#define DIM 128
#define BM 128

typedef __attribute__((ext_vector_type(8))) short bf16x8;
typedef __attribute__((ext_vector_type(16))) float f32x16;

__device__ inline unsigned short f2b(float x) {  // fp32 -> bf16 RNE
    unsigned int u = __float_as_uint(x);
    unsigned int r = (u + 0x7fffu + ((u >> 16) & 1u)) >> 16;
    return (unsigned short)r;
}
__device__ inline float blo(unsigned int u) { return __uint_as_float(u << 16); }
__device__ inline float bhi(unsigned int u) { return __uint_as_float(u & 0xffff0000u); }

// ---------------- histogram: out-degree (by row) and in-count (by col) -----
__global__ __launch_bounds__(256) void hist_kernel(const int* __restrict__ row,
                                                   const int* __restrict__ col,
                                                   int* __restrict__ degi,
                                                   int* __restrict__ cnt, int E) {
    int e = blockIdx.x * 256 + threadIdx.x;
    if (e < E) {
        atomicAdd(&degi[row[e]], 1);
        atomicAdd(&cnt[col[e]], 1);
    }
}

// ---------------- 3-phase exclusive scan of cnt -> off ----------------------
__global__ __launch_bounds__(256) void scan1_kernel(const int* __restrict__ cnt,
                                                    int* __restrict__ bsum, int n) {
    __shared__ int buf[256];
    int i = blockIdx.x * 256 + threadIdx.x;
    buf[threadIdx.x] = (i < n) ? cnt[i] : 0;
    __syncthreads();
    for (int s = 128; s > 0; s >>= 1) {
        if (threadIdx.x < s) buf[threadIdx.x] += buf[threadIdx.x + s];
        __syncthreads();
    }
    if (threadIdx.x == 0) bsum[blockIdx.x] = buf[0];
}

__global__ __launch_bounds__(256) void scan2_kernel(int* __restrict__ bsum, int nb) {
    __shared__ int buf[256];
    int tid = threadIdx.x;
    int v = (tid < nb) ? bsum[tid] : 0;
    buf[tid] = v;
    __syncthreads();
    for (int s = 1; s < 256; s <<= 1) {
        int add = (tid >= s) ? buf[tid - s] : 0;
        __syncthreads();
        buf[tid] += add;
        __syncthreads();
    }
    if (tid < nb) bsum[tid] = buf[tid] - v;  // exclusive block offsets
}

// off[] exclusive scan; re-init cnt[] as scatter cursor; fused dinv
__global__ __launch_bounds__(256) void scan3_kernel(int* __restrict__ cnt,
                                                    const int* __restrict__ bsum,
                                                    int* __restrict__ off,
                                                    const int* __restrict__ degi,
                                                    float* __restrict__ dinv, int n) {
    __shared__ int buf[256];
    int tid = threadIdx.x;
    int i = blockIdx.x * 256 + tid;
    int v = (i < n) ? cnt[i] : 0;
    buf[tid] = v;
    __syncthreads();
    for (int s = 1; s < 256; s <<= 1) {
        int add = (tid >= s) ? buf[tid - s] : 0;
        __syncthreads();
        buf[tid] += add;
        __syncthreads();
    }
    int excl = bsum[blockIdx.x] + buf[tid] - v;
    if (i < n) {
        off[i] = excl;
        cnt[i] = excl;
        dinv[i] = rsqrtf(fmaxf((float)degi[i], 1.0f));
    }
    if (i == n - 1) off[n] = excl + v;
}

__global__ __launch_bounds__(256) void scatter_kernel(const int* __restrict__ row,
                                                      const int* __restrict__ col,
                                                      int* __restrict__ cursor,
                                                      int* __restrict__ csr_row, int E) {
    int e = blockIdx.x * 256 + threadIdx.x;
    if (e < E) {
        int slot = atomicAdd(&cursor[col[e]], 1);
        csr_row[slot] = row[e];
    }
}

// ---------------- transform: bf16 MFMA GEMM --------------------------------
// h1 = hin @ Wt^T + bt (fp32 acc, stored bf16) ; a = tanh(h1 . Wg + bg)*dinv
// 256 threads = 4 waves; 128x128 tile; wave w owns rows w*32..w*32+31.
// LDS 65KB -> 2 blocks/CU. 16B-chunk XOR swizzle (chunk ^ (row&15)).
__global__ __launch_bounds__(256) void transform_kernel(
    const float* __restrict__ hin, const float* __restrict__ Wt,
    const float* __restrict__ bt, const float* __restrict__ Wg,
    const float* __restrict__ bg, const float* __restrict__ dinv,
    unsigned short* __restrict__ h1b, float* __restrict__ aout, int n)
{
    __shared__ __align__(16) unsigned short h_s[BM * DIM];   // 32 KB
    __shared__ __align__(16) unsigned short w_s[DIM * DIM];  // 32 KB
    __shared__ float p_s[BM];

    const int tid = threadIdx.x;
    const int node0 = blockIdx.x * BM;
    const int lane = tid & 63;
    const int wv = tid >> 6;

    // ---- stage H and W as swizzled bf16 ----
#pragma unroll
    for (int it = 0; it < 16; ++it) {
        int g = it * 256 + tid;          // 4096 float4 slots
        int r = g >> 5;                  // row 0..127
        int c4 = g & 31;                 // float4 index (4 cols)
        int src = node0 + r;
        if (src >= n) src = n - 1;
        float4 hv = *(const float4*)(hin + (size_t)src * DIM + c4 * 4);
        float4 wvv = *(const float4*)(Wt + (size_t)r * DIM + c4 * 4);
        int chunk = (c4 >> 1) ^ (r & 15);
        int base = r * DIM + chunk * 8 + (c4 & 1) * 4;
        h_s[base + 0] = f2b(hv.x); h_s[base + 1] = f2b(hv.y);
        h_s[base + 2] = f2b(hv.z); h_s[base + 3] = f2b(hv.w);
        w_s[base + 0] = f2b(wvv.x); w_s[base + 1] = f2b(wvv.y);
        w_s[base + 2] = f2b(wvv.z); w_s[base + 3] = f2b(wvv.w);
    }
    __syncthreads();

    // ---- MFMA K-loop: 8 steps of k=16, 4 col-frags of 32 ----
    f32x16 acc[4] = {};
    const int l31 = lane & 31;
    const int asel = lane >> 5;
    const int swz = l31 & 15;           // (abs row) & 15 == (lane&31)&15
    const unsigned short* ha = h_s + (wv * 32 + l31) * DIM;
#pragma unroll
    for (int ks = 0; ks < 8; ++ks) {
        int ch = ((ks * 2 + asel) ^ swz) * 8;
        bf16x8 av = *(const bf16x8*)(ha + ch);
#pragma unroll
        for (int cf = 0; cf < 4; ++cf) {
            bf16x8 bv = *(const bf16x8*)(w_s + (cf * 32 + l31) * DIM + ch);
            acc[cf] = __builtin_amdgcn_mfma_f32_32x32x16_bf16(av, bv, acc[cf], 0, 0, 0);
        }
    }
    __syncthreads();  // done reading staged tiles

    // ---- epilogue: bias, gate partials, h1 (bf16) into plain LDS ----
    float btc[4], wgc[4];
#pragma unroll
    for (int cf = 0; cf < 4; ++cf) {
        btc[cf] = bt[cf * 32 + l31];
        wgc[cf] = Wg[cf * 32 + l31];
    }
    float p[16];
#pragma unroll
    for (int q = 0; q < 16; ++q) p[q] = 0.0f;
#pragma unroll
    for (int cf = 0; cf < 4; ++cf) {
#pragma unroll
        for (int q = 0; q < 16; ++q) {
            float v = acc[cf][q] + btc[cf];
            p[q] = fmaf(v, wgc[cf], p[q]);
            int row = (q & 3) + 8 * (q >> 2) + 4 * asel;   // 0..31
            h_s[(wv * 32 + row) * DIM + cf * 32 + l31] = f2b(v);
        }
    }
    // reduce p over the 32 lanes of each half-wave
#pragma unroll
    for (int m = 1; m < 32; m <<= 1) {
#pragma unroll
        for (int q = 0; q < 16; ++q) p[q] += __shfl_xor(p[q], m, 64);
    }
    if (l31 == 0) {
#pragma unroll
        for (int q = 0; q < 16; ++q) {
            int row = (q & 3) + 8 * (q >> 2) + 4 * asel;
            p_s[wv * 32 + row] = p[q];
        }
    }
    __syncthreads();

    // ---- coalesced bf16 copy-out ----
#pragma unroll
    for (int it = 0; it < 8; ++it) {
        int g = it * 256 + tid;          // 2048 16B chunks
        int r = g >> 4;
        int c = g & 15;
        int4 v = *(const int4*)(h_s + r * DIM + c * 8);
        int dst = node0 + r;
        if (dst < n) *(int4*)(h1b + (size_t)dst * DIM + c * 8) = v;
    }

    // ---- gate finalize ----
    if (tid < BM) {
        int node = node0 + tid;
        if (node < n) aout[node] = tanhf(p_s[tid] + bg[0]) * dinv[node];
    }
}

// ---------------- aggregation: out[c] = relu(dinv[c]*sum(a[r]*h1[r]) + h1[c])
// one wave per node; lane owns 2 bf16 (uint) of the 128-dim row.
__global__ __launch_bounds__(256) void agg_kernel(
    const int* __restrict__ off, const int* __restrict__ csr_row,
    const float* __restrict__ a, const float* __restrict__ dinv,
    const unsigned short* __restrict__ h1b, float* __restrict__ out, int n)
{
    int node = blockIdx.x * 4 + (threadIdx.x >> 6);
    if (node >= n) return;
    int lane = threadIdx.x & 63;
    int beg = off[node], end = off[node + 1];
    const unsigned int* hb = (const unsigned int*)h1b;  // 64 uints per row
    float s0x = 0.f, s0y = 0.f, s1x = 0.f, s1y = 0.f;
    float s2x = 0.f, s2y = 0.f, s3x = 0.f, s3y = 0.f;
    int s = beg;
    for (; s + 4 <= end; s += 4) {
        int r0 = csr_row[s], r1 = csr_row[s + 1], r2 = csr_row[s + 2], r3 = csr_row[s + 3];
        float a0 = a[r0], a1 = a[r1], a2 = a[r2], a3 = a[r3];
        unsigned int u0 = hb[(size_t)r0 * 64 + lane];
        unsigned int u1 = hb[(size_t)r1 * 64 + lane];
        unsigned int u2 = hb[(size_t)r2 * 64 + lane];
        unsigned int u3 = hb[(size_t)r3 * 64 + lane];
        s0x = fmaf(a0, blo(u0), s0x); s0y = fmaf(a0, bhi(u0), s0y);
        s1x = fmaf(a1, blo(u1), s1x); s1y = fmaf(a1, bhi(u1), s1y);
        s2x = fmaf(a2, blo(u2), s2x); s2y = fmaf(a2, bhi(u2), s2y);
        s3x = fmaf(a3, blo(u3), s3x); s3y = fmaf(a3, bhi(u3), s3y);
    }
    for (; s < end; ++s) {
        int r0 = csr_row[s];
        float a0 = a[r0];
        unsigned int u0 = hb[(size_t)r0 * 64 + lane];
        s0x = fmaf(a0, blo(u0), s0x); s0y = fmaf(a0, bhi(u0), s0y);
    }
    float dv = dinv[node];
    unsigned int ur = hb[(size_t)node * 64 + lane];
    float2 o;
    o.x = fmaxf(fmaf(dv, s0x + s1x + s2x + s3x, blo(ur)), 0.0f);
    o.y = fmaxf(fmaf(dv, s0y + s1y + s2y + s3y, bhi(ur)), 0.0f);
    ((float2*)out)[(size_t)node * 64 + lane] = o;
}

extern "C" void kernel_launch(void* const* d_in, const int* in_sizes, int n_in,
                              void* d_out, int out_size, void* d_ws, size_t ws_size,
                              hipStream_t stream) {
    const float* x    = (const float*)d_in[0];
    const int*   edge = (const int*)d_in[1];
    const float* Wt   = (const float*)d_in[2];
    const float* bt   = (const float*)d_in[3];
    const float* Wg   = (const float*)d_in[4];
    const float* bg   = (const float*)d_in[5];
    float* out = (float*)d_out;

    const int n = in_sizes[0] / DIM;      // 50000
    const int E = in_sizes[1] / 2;        // 600000
    const int* row = edge;
    const int* col = edge + E;

    // workspace layout (float units)
    float* ws = (float*)d_ws;
    unsigned short* h1b = (unsigned short*)ws;   // n*DIM bf16 = 3,200,000 floats
    float* dinv = ws + 3200000;                  // n (pad 50048)
    float* a    = ws + 3250048;                  // n
    int*   cnt  = (int*)(ws + 3300096);          // n (also scatter cursor)
    int*   off  = (int*)(ws + 3350144);          // n+1 (pad 50304)
    int*   bsum = (int*)(ws + 3400448);          // 256
    int*   degi = (int*)(ws + 3400704);          // n
    int*   csr  = (int*)(ws + 3450752);          // E

    const int nb = (n + 255) / 256;

    // ---- edge-structure preprocessing (shared by both layers) ----
    hipMemsetAsync(degi, 0, (size_t)n * sizeof(int), stream);
    hipMemsetAsync(cnt, 0, (size_t)n * sizeof(int), stream);
    hist_kernel<<<(E + 255) / 256, 256, 0, stream>>>(row, col, degi, cnt, E);
    scan1_kernel<<<nb, 256, 0, stream>>>(cnt, bsum, n);
    scan2_kernel<<<1, 256, 0, stream>>>(bsum, nb);
    scan3_kernel<<<nb, 256, 0, stream>>>(cnt, bsum, off, degi, dinv, n);
    scatter_kernel<<<(E + 255) / 256, 256, 0, stream>>>(row, col, cnt, csr, E);

    // ---- two FA layers ----
    const int gt = (n + BM - 1) / BM;
    for (int l = 0; l < 2; ++l) {
        const float* hin = (l == 0) ? x : out;
        const float* Wtl = Wt + (size_t)l * DIM * DIM;
        const float* btl = bt + (size_t)l * DIM;
        const float* Wgl = Wg + (size_t)l * DIM;
        const float* bgl = bg + l;

        transform_kernel<<<gt, 256, 0, stream>>>(
            hin, Wtl, btl, Wgl, bgl, dinv, h1b, a, n);
        agg_kernel<<<(n + 3) / 4, 256, 0, stream>>>(off, csr, a, dinv, h1b, out, n);
    }
}